// Round 9
// baseline (335.383 us; speedup 1.0000x reference)
//
#include <hip/hip_runtime.h>

#define DH 128
#define NBMAX 1024   // max coarse bins (N <= 131072)
#define BCH 4096     // edges per block in CSR build

typedef __attribute__((ext_vector_type(8))) short s16x8;
typedef __attribute__((ext_vector_type(4))) float f32x4;
typedef __attribute__((ext_vector_type(4))) uint u32x4;
typedef __attribute__((ext_vector_type(4))) int i32x4;

__device__ __forceinline__ ushort f2bf(float x) {
  uint u = __builtin_bit_cast(uint, x);
  u = (u + 0x7FFF + ((u >> 16) & 1)) >> 16;  // RTNE
  return (ushort)u;
}
__device__ __forceinline__ float bfl2f(uint u) {  // low ushort -> float
  return __builtin_bit_cast(float, u << 16);
}
__device__ __forceinline__ float bfh2f(uint u) {  // high ushort -> float
  return __builtin_bit_cast(float, u & 0xFFFF0000u);
}

// ---------------- prep: Wt bf16 transpose (3 layers) + chist zero ----------------
__global__ __launch_bounds__(512) void prep_kernel(const float* __restrict__ W0,
                                                   const float* __restrict__ W1,
                                                   const float* __restrict__ W2,
                                                   ushort* __restrict__ Wtb,
                                                   int* __restrict__ chist) {
  int b = blockIdx.x, t = threadIdx.x;
  if (b < 96) {  // 96*512 = 49152 = 3*16384 transpose elements
    int g = b * 512 + t;
    int layer = g >> 14, i = g & 16383;
    const float* W = layer == 0 ? W0 : (layer == 1 ? W1 : W2);
    int col = i >> 7, k = i & 127;
    Wtb[(size_t)layer * DH * DH + (size_t)col * DH + k] = f2bf(W[(size_t)k * DH + col]);
  } else {       // 8 blocks * 512 * 4 = 16384 ints: zero chist
    int idx = ((b - 96) * 512 + t) * 4;
    *(i32x4*)(chist + idx) = (i32x4){0, 0, 0, 0};
  }
}

// ---------------- shared GEMM body: hb(bf16) = x @ W ; fused el/er ----------------
// 512 threads = 8 waves; tile 128 rows x 128 cols; mfma 16x16x32 bf16
template <bool XF32>
__device__ __forceinline__ void gemm_body(ushort* __restrict__ As, ushort* __restrict__ Bs,
                                          const void* __restrict__ xin,
                                          const ushort* __restrict__ Wtb,
                                          const float* __restrict__ al,
                                          const float* __restrict__ ar,
                                          ushort* __restrict__ hb, float* __restrict__ el,
                                          float* __restrict__ er, int M, int R0, int t) {
  // stage B (bf16, already transposed): 2048 16B-blocks
  for (int i = t; i < 2048; i += 512) {
    int col = i >> 4, kb = i & 15;
    s16x8 v = *(const s16x8*)(Wtb + (size_t)col * DH + kb * 8);
    *(s16x8*)(&Bs[col * DH + ((kb ^ (col & 15)) * 8)]) = v;
  }
  // stage A: 2048 16B-blocks (128 rows)
  for (int i = t; i < 2048; i += 512) {
    int row = i >> 4, kb = i & 15;
    int gr = R0 + row;
    s16x8 v;
    if (gr < M) {
      if constexpr (XF32) {
        const float4* p = (const float4*)((const float*)xin + (size_t)gr * DH + kb * 8);
        float4 a = p[0], b = p[1];
        v[0] = (short)f2bf(a.x); v[1] = (short)f2bf(a.y);
        v[2] = (short)f2bf(a.z); v[3] = (short)f2bf(a.w);
        v[4] = (short)f2bf(b.x); v[5] = (short)f2bf(b.y);
        v[6] = (short)f2bf(b.z); v[7] = (short)f2bf(b.w);
      } else {
        v = *(const s16x8*)((const ushort*)xin + (size_t)gr * DH + kb * 8);
      }
    } else {
      v = (s16x8)0;
    }
    *(s16x8*)(&As[row * DH + ((kb ^ (row & 15)) * 8)]) = v;
  }
  __syncthreads();

  int w = t >> 6, lane = t & 63;  // 8 waves x 16 rows
  int li = lane & 15, lq = lane >> 4;
  f32x4 acc[8] = {};
  int arow = w * 16 + li;
#pragma unroll
  for (int kc = 0; kc < 4; ++kc) {
    int kb = kc * 4 + lq;
    s16x8 af = *(const s16x8*)(&As[arow * DH + ((kb ^ (arow & 15)) * 8)]);
#pragma unroll
    for (int cf = 0; cf < 8; ++cf) {
      int bcol = cf * 16 + li;
      s16x8 bf = *(const s16x8*)(&Bs[bcol * DH + ((kb ^ (bcol & 15)) * 8)]);
      acc[cf] = __builtin_amdgcn_mfma_f32_16x16x32_bf16(af, bf, acc[cf], 0, 0, 0);
    }
  }

  int Rw = R0 + w * 16;
  // fused el/er: lane holds D[row=lq*4+r][col=cf*16+li]
  float alv[8], arv[8];
#pragma unroll
  for (int cf = 0; cf < 8; ++cf) {
    alv[cf] = al[cf * 16 + li];
    arv[cf] = ar[cf * 16 + li];
  }
#pragma unroll
  for (int r = 0; r < 4; ++r) {
    float sl = 0.f, sr = 0.f;
#pragma unroll
    for (int cf = 0; cf < 8; ++cf) {
      sl += acc[cf][r] * alv[cf];
      sr += acc[cf][r] * arv[cf];
    }
#pragma unroll
    for (int off = 1; off <= 8; off <<= 1) {
      sl += __shfl_xor(sl, off);
      sr += __shfl_xor(sr, off);
    }
    int grow = Rw + lq * 4 + r;
    if (li == 0 && grow < M) {
      el[grow] = sl;
      er[grow] = sr;
    }
  }

  // h store via LDS repack. Each wave reads/writes ONLY its own 16 As rows.
  ushort* hl = &As[w * 16 * DH];
#pragma unroll
  for (int cf = 0; cf < 8; ++cf)
#pragma unroll
    for (int r = 0; r < 4; ++r) hl[(lq * 4 + r) * DH + cf * 16 + li] = f2bf(acc[cf][r]);
#pragma unroll
  for (int p = 0; p < 4; ++p) {
    int row = lane >> 2;
    int blk = (lane & 3) + p * 4;
    s16x8 v = *(const s16x8*)(&hl[row * DH + blk * 8]);
    int grow = Rw + row;
    if (grow < M)
      __builtin_nontemporal_store(v, (s16x8*)(hb + (size_t)grow * DH + blk * 8));
  }
}

// ---------------- bf16-input GEMM (layers 1,2) ----------------
__global__ __launch_bounds__(512) void gemm_kernel(const ushort* __restrict__ xin,
                                                   const ushort* __restrict__ Wtb,
                                                   const float* __restrict__ al,
                                                   const float* __restrict__ ar,
                                                   ushort* __restrict__ hb,
                                                   float* __restrict__ el,
                                                   float* __restrict__ er, int M) {
  __shared__ ushort As[128 * DH];
  __shared__ ushort Bs[DH * DH];
  gemm_body<false>(As, Bs, xin, Wtb, al, ar, hb, el, er, M, blockIdx.x * 128, threadIdx.x);
}

// ---------------- fused layer-0 GEMM (fp32 input) + chist (independent work) ----------------
__global__ __launch_bounds__(512) void gemm0_chist_kernel(const float* __restrict__ feat,
                                                          const ushort* __restrict__ Wtb,
                                                          const float* __restrict__ al,
                                                          const float* __restrict__ ar,
                                                          ushort* __restrict__ hb,
                                                          float* __restrict__ el,
                                                          float* __restrict__ er, int M,
                                                          const int* __restrict__ dst,
                                                          int* __restrict__ chist, int E, int NB,
                                                          int GB) {
  __shared__ ushort As[128 * DH];
  __shared__ ushort Bs[DH * DH];
  int b = blockIdx.x, t = threadIdx.x;
  if (b < GB) {
    gemm_body<true>(As, Bs, feat, Wtb, al, ar, hb, el, er, M, b * 128, t);
    return;
  }
  // chist role: LDS histogram aliases As (4 KB needed)
  int* h = (int*)As;
  for (int i = t; i < NB; i += 512) h[i] = 0;
  __syncthreads();
  int base = (b - GB) * BCH;
  int n = min(BCH, E - base);
  for (int i0 = 0; i0 < n; i0 += 2048) {
    uint d[4]; bool ok[4];
#pragma unroll
    for (int k = 0; k < 4; ++k) {
      int i = i0 + k * 512 + t;
      ok[k] = i < n;
      d[k] = ok[k] ? (uint)dst[base + i] : 0u;
    }
#pragma unroll
    for (int k = 0; k < 4; ++k)
      if (ok[k]) atomicAdd(&h[d[k] >> 7], 1);
  }
  __syncthreads();
  for (int i = t; i < NB; i += 512)
    if (h[i]) atomicAdd(&chist[i * 16], h[i]);
}

// ---------------- CSR scan ----------------
__global__ __launch_bounds__(256) void cscan_kernel(const int* __restrict__ chist,
                                                    int* __restrict__ cbase, int* __restrict__ ccur,
                                                    int* __restrict__ rowptr, int N, int NB, int E) {
  __shared__ int lds[256];
  int t = threadIdx.x;
  int v[4], s = 0;
#pragma unroll
  for (int j = 0; j < 4; ++j) {
    int idx = t * 4 + j;
    v[j] = (idx < NB) ? chist[idx * 16] : 0;
    s += v[j];
  }
  lds[t] = s;
  __syncthreads();
  for (int off = 1; off < 256; off <<= 1) {
    int add = (t >= off) ? lds[t - off] : 0;
    __syncthreads();
    lds[t] += add;
    __syncthreads();
  }
  int run = t ? lds[t - 1] : 0;
#pragma unroll
  for (int j = 0; j < 4; ++j) {
    int idx = t * 4 + j;
    if (idx < NB) {
      cbase[idx] = run;
      ccur[idx * 16] = run;
    }
    run += v[j];
  }
  if (t == 255) cbase[NB] = lds[255];
  if (t == 0) rowptr[N] = E;
}

// ---------------- binscat: 8-deep predicated batches ----------------
__global__ __launch_bounds__(256) void binscat_kernel(const int* __restrict__ src,
                                                      const int* __restrict__ dst,
                                                      int* __restrict__ ccur,
                                                      uint* __restrict__ puv, int E, int NB) {
  __shared__ int h[NBMAX];
  __shared__ int gb[NBMAX];
  int t = threadIdx.x;
  int base = blockIdx.x * BCH;
  int n = min(BCH, E - base);
  for (int i = t; i < NB; i += 256) h[i] = 0;
  __syncthreads();
  for (int i0 = 0; i0 < n; i0 += 2048) {
    uint d[8]; bool ok[8];
#pragma unroll
    for (int k = 0; k < 8; ++k) {
      int i = i0 + k * 256 + t;
      ok[k] = i < n;
      d[k] = ok[k] ? (uint)dst[base + i] : 0u;
    }
#pragma unroll
    for (int k = 0; k < 8; ++k)
      if (ok[k]) atomicAdd(&h[d[k] >> 7], 1);
  }
  __syncthreads();
  // reserve a contiguous run per bin for this block; reset h as local cursor
  for (int i = t; i < NB; i += 256) {
    int c = h[i];
    gb[i] = c ? atomicAdd(&ccur[i * 16], c) : 0;
    h[i] = 0;
  }
  __syncthreads();
  for (int i0 = 0; i0 < n; i0 += 2048) {
    uint d[8], s[8]; bool ok[8];
#pragma unroll
    for (int k = 0; k < 8; ++k) {
      int i = i0 + k * 256 + t;
      ok[k] = i < n;
      d[k] = ok[k] ? (uint)dst[base + i] : 0u;
      s[k] = ok[k] ? (uint)src[base + i] : 0u;
    }
    int p[8];
#pragma unroll
    for (int k = 0; k < 8; ++k)
      if (ok[k]) {
        int bb = d[k] >> 7;
        p[k] = gb[bb] + atomicAdd(&h[bb], 1);
      }
#pragma unroll
    for (int k = 0; k < 8; ++k)
      if (ok[k]) puv[p[k]] = ((d[k] & 127u) << 25) | s[k];
  }
}

// ---------------- finesort: 8-deep predicated batches ----------------
__global__ __launch_bounds__(256) void finesort_kernel(const uint* __restrict__ puv,
                                                       const int* __restrict__ cbase,
                                                       int* __restrict__ rowptr,
                                                       int* __restrict__ ssrc, int N) {
  int b = blockIdx.x;
  int base = cbase[b];
  int cnt = cbase[b + 1] - base;
  __shared__ int ncnt[128], nincl[128], noff[128];
  int t = threadIdx.x;
  if (t < 128) ncnt[t] = 0;
  __syncthreads();
  for (int i0 = 0; i0 < cnt; i0 += 2048) {
    uint e[8]; bool ok[8];
#pragma unroll
    for (int k = 0; k < 8; ++k) {
      int i = i0 + k * 256 + t;
      ok[k] = i < cnt;
      e[k] = ok[k] ? puv[base + i] : 0u;
    }
#pragma unroll
    for (int k = 0; k < 8; ++k)
      if (ok[k]) atomicAdd(&ncnt[e[k] >> 25], 1);
  }
  __syncthreads();
  if (t < 128) nincl[t] = ncnt[t];
  __syncthreads();
  for (int off = 1; off < 128; off <<= 1) {
    int add = (t < 128 && t >= off) ? nincl[t - off] : 0;
    __syncthreads();
    if (t < 128) nincl[t] += add;
    __syncthreads();
  }
  if (t < 128) {
    noff[t] = nincl[t] - ncnt[t];
    int node = (b << 7) + t;
    if (node < N) rowptr[node] = base + noff[t];
    ncnt[t] = 0;  // reuse as cursor
  }
  __syncthreads();
  for (int i0 = 0; i0 < cnt; i0 += 2048) {
    uint e[8]; bool ok[8];
#pragma unroll
    for (int k = 0; k < 8; ++k) {
      int i = i0 + k * 256 + t;
      ok[k] = i < cnt;
      e[k] = ok[k] ? puv[base + i] : 0u;
    }
    int p[8];
#pragma unroll
    for (int k = 0; k < 8; ++k)
      if (ok[k]) {
        int ln = e[k] >> 25;
        p[k] = base + noff[ln] + atomicAdd(&ncnt[ln], 1);
      }
#pragma unroll
    for (int k = 0; k < 8; ++k)
      if (ok[k]) ssrc[p[k]] = (int)(e[k] & 0x1FFFFFFu);
  }
}

// ---------------- fused edge-softmax + aggregation (one wave per dst node) ----------------
// deg<=32 fast path: ALL row-gathers issued up front (8 quads in flight, one
// latency exposure per node). Wave-uniform k*4<deg guards skip dead blocks.
// Padded lanes in a partial quad gather row 0 (hot, wgt=0).
// FINAL=0: write bf16 xb (non-temporal); FINAL=1: write fp32 d_out.
template <int FINAL>
__global__ __launch_bounds__(256) void agg_kernel(const ushort* __restrict__ hb,
                                                  const float* __restrict__ el,
                                                  const float* __restrict__ er,
                                                  const int* __restrict__ rowptr,
                                                  const int* __restrict__ ssrc,
                                                  const float* __restrict__ bias,
                                                  void* __restrict__ outv, int M) {
  int wid = (blockIdx.x * blockDim.x + threadIdx.x) >> 6;  // node id
  int lane = threadIdx.x & 63;
  if (wid >= M) return;
  int begin = rowptr[wid], end = rowptr[wid + 1];
  int deg = end - begin;

  if (deg > 64) {  // rare high-degree path: self-contained, float2-per-lane
    float er_d = er[wid];
    float mx = -1e30f;
    for (int e = begin + lane; e < end; e += 64) {
      float s = el[ssrc[e]] + er_d;
      s = s > 0.f ? s : 0.2f * s;
      mx = fmaxf(mx, s);
    }
#pragma unroll
    for (int off = 32; off; off >>= 1) mx = fmaxf(mx, __shfl_xor(mx, off));
    float acc0 = 0.f, acc1 = 0.f, ssum_l = 0.f;
    for (int base = begin; base < end; base += 64) {
      int n = min(64, end - base);
      int e = base + lane;
      int idx = 0;
      float wgt = 0.f;
      if (lane < n) {
        idx = ssrc[e];
        float sc = el[idx] + er_d;
        sc = sc > 0.f ? sc : 0.2f * sc;
        wgt = __expf(sc - mx);
      }
      ssum_l += wgt;
      for (int j = 0; j < n; ++j) {
        int s = __shfl(idx, j);
        float wg = __shfl(wgt, j);
        uint u = ((const uint*)(hb + (size_t)s * DH))[lane];
        acc0 += wg * bfl2f(u);
        acc1 += wg * bfh2f(u);
      }
    }
#pragma unroll
    for (int off = 32; off; off >>= 1) ssum_l += __shfl_xor(ssum_l, off);
    float inv = 1.f / ssum_l;
    float2 b2 = ((const float2*)bias)[lane];
    float o0 = acc0 * inv + b2.x;
    float o1 = acc1 * inv + b2.y;
    if constexpr (FINAL) {
      ((float2*)((float*)outv + (size_t)wid * DH))[lane] = make_float2(o0, o1);
    } else {
      uint p = (uint)f2bf(o0) | ((uint)f2bf(o1) << 16);
      ((uint*)((ushort*)outv + (size_t)wid * DH))[lane] = p;
    }
    return;
  }

  float acc[8] = {};
  float inv = 0.f;
  if (deg > 0) {
    // lane j owns edge begin+j: index, el-gather, leaky, exp all lane-parallel
    int e = begin + lane;
    int idx = (e < end) ? ssrc[e] : 0;
    float sc = -1e30f;
    if (e < end) {
      sc = el[idx] + er[wid];
      sc = sc > 0.f ? sc : 0.2f * sc;
    }
    float mx = sc;
#pragma unroll
    for (int off = 32; off; off >>= 1) mx = fmaxf(mx, __shfl_xor(mx, off));
    float wgt = (e < end) ? __expf(sc - mx) : 0.f;
    float ssum = wgt;
#pragma unroll
    for (int off = 32; off; off >>= 1) ssum += __shfl_xor(ssum, off);
    inv = 1.f / ssum;

    int q = lane >> 4, cl = lane & 15;
    const uint4* hb4 = (const uint4*)hb;  // row = 16 uint4

    if (deg <= 32) {
      // ---- fast path: up to 8 quads (32 edges) all in flight ----
      uint4 u[8];
      float wq[8];
#pragma unroll
      for (int k = 0; k < 8; ++k) {
        if (k * 4 < deg) {  // wave-uniform
          int ej = k * 4 + q;          // ej<36; dead lanes (ej>=deg) hit row 0
          int s = __shfl(idx, ej & 31);
          wq[k] = __shfl(wgt, ej & 31);
          u[k] = hb4[(size_t)s * 16 + cl];
        }
      }
#pragma unroll
      for (int k = 0; k < 8; ++k) {
        if (k * 4 < deg) {  // wave-uniform
          float wk = wq[k];
          acc[0] += wk * bfl2f(u[k].x); acc[1] += wk * bfh2f(u[k].x);
          acc[2] += wk * bfl2f(u[k].y); acc[3] += wk * bfh2f(u[k].y);
          acc[4] += wk * bfl2f(u[k].z); acc[5] += wk * bfh2f(u[k].z);
          acc[6] += wk * bfl2f(u[k].w); acc[7] += wk * bfh2f(u[k].w);
        }
      }
    } else {
      // ---- mid path: 32 < deg <= 64, 16 edges per step ----
      for (int j = 0; j < deg; j += 16) {
        uint4 u[4];
        float wq[4];
#pragma unroll
        for (int k = 0; k < 4; ++k) {
          int ej = j + k * 4 + q;  // < 64 guaranteed
          int s = __shfl(idx, ej);
          wq[k] = __shfl(wgt, ej);
          u[k] = hb4[(size_t)s * 16 + cl];
        }
#pragma unroll
        for (int k = 0; k < 4; ++k) {
          acc[0] += wq[k] * bfl2f(u[k].x); acc[1] += wq[k] * bfh2f(u[k].x);
          acc[2] += wq[k] * bfl2f(u[k].y); acc[3] += wq[k] * bfh2f(u[k].y);
          acc[4] += wq[k] * bfl2f(u[k].z); acc[5] += wq[k] * bfh2f(u[k].z);
          acc[6] += wq[k] * bfl2f(u[k].w); acc[7] += wq[k] * bfh2f(u[k].w);
        }
      }
    }
    // combine the 4 edge-quarters: lanes sharing (lane&15) sum up
#pragma unroll
    for (int i = 0; i < 8; ++i) {
      acc[i] += __shfl_xor(acc[i], 16);
      acc[i] += __shfl_xor(acc[i], 32);
    }
  }
  // deg==0: acc=0, inv=0 -> out = bias
  if (lane < 16) {
    float4 b0 = ((const float4*)bias)[lane * 2];
    float4 b1 = ((const float4*)bias)[lane * 2 + 1];
    float o[8];
    o[0] = acc[0] * inv + b0.x; o[1] = acc[1] * inv + b0.y;
    o[2] = acc[2] * inv + b0.z; o[3] = acc[3] * inv + b0.w;
    o[4] = acc[4] * inv + b1.x; o[5] = acc[5] * inv + b1.y;
    o[6] = acc[6] * inv + b1.z; o[7] = acc[7] * inv + b1.w;
    if constexpr (FINAL) {
      f32x4 p0 = {o[0], o[1], o[2], o[3]};
      f32x4 p1 = {o[4], o[5], o[6], o[7]};
      float* op = (float*)outv + (size_t)wid * DH + lane * 8;
      *(f32x4*)op = p0;
      *(f32x4*)(op + 4) = p1;
    } else {
      u32x4 p;
      p.x = (uint)f2bf(o[0]) | ((uint)f2bf(o[1]) << 16);
      p.y = (uint)f2bf(o[2]) | ((uint)f2bf(o[3]) << 16);
      p.z = (uint)f2bf(o[4]) | ((uint)f2bf(o[5]) << 16);
      p.w = (uint)f2bf(o[6]) | ((uint)f2bf(o[7]) << 16);
      __builtin_nontemporal_store(p, (u32x4*)((ushort*)outv + (size_t)wid * DH) + lane);
    }
  }
}

extern "C" void kernel_launch(void* const* d_in, const int* in_sizes, int n_in,
                              void* d_out, int out_size, void* d_ws, size_t ws_size,
                              hipStream_t stream) {
  const float* feat = (const float*)d_in[0];
  const int* src = (const int*)d_in[1];
  const int* dst = (const int*)d_in[2];
  const int N = in_sizes[0] / DH;  // 100000
  const int E = in_sizes[1];       // 1600000
  const int NB = (N + 127) >> 7;   // 782 coarse bins
  const float* W[3]  = {(const float*)d_in[3], (const float*)d_in[7],  (const float*)d_in[11]};
  const float* al[3] = {(const float*)d_in[4], (const float*)d_in[8],  (const float*)d_in[12]};
  const float* ar[3] = {(const float*)d_in[5], (const float*)d_in[9],  (const float*)d_in[13]};
  const float* bi[3] = {(const float*)d_in[6], (const float*)d_in[10], (const float*)d_in[14]};

  // workspace layout (~59 MB)
  char* ws = (char*)d_ws;
  size_t off = 0;
  auto alloc = [&](size_t bytes) {
    void* p = ws + off;
    off = (off + bytes + 255) & ~(size_t)255;
    return p;
  };
  ushort* hb   = (ushort*)alloc((size_t)N * DH * sizeof(ushort));  // 25.6 MB
  ushort* xb   = (ushort*)alloc((size_t)N * DH * sizeof(ushort));  // 25.6 MB
  float* el    = (float*)alloc((size_t)N * sizeof(float));
  float* er    = (float*)alloc((size_t)N * sizeof(float));
  int* rowptr  = (int*)alloc((size_t)(N + 1) * sizeof(int));
  int* ssrc    = (int*)alloc((size_t)E * sizeof(int));             // 6.4 MB
  ushort* Wtb  = (ushort*)alloc((size_t)3 * DH * DH * sizeof(ushort));
  int* chist   = (int*)alloc((size_t)NBMAX * 16 * sizeof(int));    // 64 KB padded
  int* cbase   = (int*)alloc((size_t)(NBMAX + 1) * sizeof(int));
  int* ccur    = (int*)alloc((size_t)NBMAX * 16 * sizeof(int));    // 64 KB padded
  // puv aliases xb: dead before agg0 writes xb, used only by binscat/finesort
  uint* puv    = (uint*)xb;

  int ebl = (E + BCH - 1) / BCH;   // 391
  int GB = (N + 127) / 128;        // 782 gemm tiles

  // ---- prep: Wt transpose (all layers) + chist zero ----
  prep_kernel<<<104, 512, 0, stream>>>(W[0], W[1], W[2], Wtb, chist);
  // ---- layer-0 GEMM fused with chist (independent work streams) ----
  gemm0_chist_kernel<<<GB + ebl, 512, 0, stream>>>(feat, Wtb, al[0], ar[0], hb, el, er, N,
                                                   dst, chist, E, NB, GB);
  // ---- rest of CSR build ----
  cscan_kernel<<<1, 256, 0, stream>>>(chist, cbase, ccur, rowptr, N, NB, E);
  binscat_kernel<<<ebl, 256, 0, stream>>>(src, dst, ccur, puv, E, NB);
  finesort_kernel<<<NB, 256, 0, stream>>>(puv, cbase, rowptr, ssrc, N);

  // ---- layer 0 agg, then layers 1,2 ----
  agg_kernel<0><<<(N + 3) / 4, 256, 0, stream>>>(hb, el, er, rowptr, ssrc, bi[0], xb, N);
  gemm_kernel<<<GB, 512, 0, stream>>>(xb, Wtb + DH * DH, al[1], ar[1], hb, el, er, N);
  agg_kernel<0><<<(N + 3) / 4, 256, 0, stream>>>(hb, el, er, rowptr, ssrc, bi[1], xb, N);
  gemm_kernel<<<GB, 512, 0, stream>>>(xb, Wtb + 2 * DH * DH, al[2], ar[2], hb, el, er, N);
  agg_kernel<1><<<(N + 3) / 4, 256, 0, stream>>>(hb, el, er, rowptr, ssrc, bi[2], d_out, N);
}

// Round 10
// 324.623 us; speedup vs baseline: 1.0331x; 1.0331x over previous
//
#include <hip/hip_runtime.h>

#define DH 128
#define NBMAX 1024   // max coarse bins (N <= 131072)
#define BCH 4096     // edges per block in CSR build

typedef __attribute__((ext_vector_type(8))) short s16x8;
typedef __attribute__((ext_vector_type(4))) float f32x4;
typedef __attribute__((ext_vector_type(4))) uint u32x4;
typedef __attribute__((ext_vector_type(4))) int i32x4;

__device__ __forceinline__ ushort f2bf(float x) {
  uint u = __builtin_bit_cast(uint, x);
  u = (u + 0x7FFF + ((u >> 16) & 1)) >> 16;  // RTNE
  return (ushort)u;
}
__device__ __forceinline__ float bfl2f(uint u) {  // low ushort -> float
  return __builtin_bit_cast(float, u << 16);
}
__device__ __forceinline__ float bfh2f(uint u) {  // high ushort -> float
  return __builtin_bit_cast(float, u & 0xFFFF0000u);
}

// ---------------- prep: Wt bf16 transpose (3 layers) + chist zero ----------------
__global__ __launch_bounds__(512) void prep_kernel(const float* __restrict__ W0,
                                                   const float* __restrict__ W1,
                                                   const float* __restrict__ W2,
                                                   ushort* __restrict__ Wtb,
                                                   int* __restrict__ chist) {
  int b = blockIdx.x, t = threadIdx.x;
  if (b < 96) {  // 96*512 = 49152 = 3*16384 transpose elements
    int g = b * 512 + t;
    int layer = g >> 14, i = g & 16383;
    const float* W = layer == 0 ? W0 : (layer == 1 ? W1 : W2);
    int col = i >> 7, k = i & 127;
    Wtb[(size_t)layer * DH * DH + (size_t)col * DH + k] = f2bf(W[(size_t)k * DH + col]);
  } else {       // 8 blocks * 512 * 4 = 16384 ints: zero chist
    int idx = ((b - 96) * 512 + t) * 4;
    *(i32x4*)(chist + idx) = (i32x4){0, 0, 0, 0};
  }
}

// ---------------- shared GEMM body: hb(bf16) = x @ W ; fused el/er ----------------
// 512 threads = 8 waves; tile 128 rows x 128 cols; mfma 16x16x32 bf16
template <bool XF32>
__device__ __forceinline__ void gemm_body(ushort* __restrict__ As, ushort* __restrict__ Bs,
                                          const void* __restrict__ xin,
                                          const ushort* __restrict__ Wtb,
                                          const float* __restrict__ al,
                                          const float* __restrict__ ar,
                                          ushort* __restrict__ hb, float* __restrict__ el,
                                          float* __restrict__ er, int M, int R0, int t) {
  // stage B (bf16, already transposed): 2048 16B-blocks
  for (int i = t; i < 2048; i += 512) {
    int col = i >> 4, kb = i & 15;
    s16x8 v = *(const s16x8*)(Wtb + (size_t)col * DH + kb * 8);
    *(s16x8*)(&Bs[col * DH + ((kb ^ (col & 15)) * 8)]) = v;
  }
  // stage A: 2048 16B-blocks (128 rows)
  for (int i = t; i < 2048; i += 512) {
    int row = i >> 4, kb = i & 15;
    int gr = R0 + row;
    s16x8 v;
    if (gr < M) {
      if constexpr (XF32) {
        const float4* p = (const float4*)((const float*)xin + (size_t)gr * DH + kb * 8);
        float4 a = p[0], b = p[1];
        v[0] = (short)f2bf(a.x); v[1] = (short)f2bf(a.y);
        v[2] = (short)f2bf(a.z); v[3] = (short)f2bf(a.w);
        v[4] = (short)f2bf(b.x); v[5] = (short)f2bf(b.y);
        v[6] = (short)f2bf(b.z); v[7] = (short)f2bf(b.w);
      } else {
        v = *(const s16x8*)((const ushort*)xin + (size_t)gr * DH + kb * 8);
      }
    } else {
      v = (s16x8)0;
    }
    *(s16x8*)(&As[row * DH + ((kb ^ (row & 15)) * 8)]) = v;
  }
  __syncthreads();

  int w = t >> 6, lane = t & 63;  // 8 waves x 16 rows
  int li = lane & 15, lq = lane >> 4;
  f32x4 acc[8] = {};
  int arow = w * 16 + li;
#pragma unroll
  for (int kc = 0; kc < 4; ++kc) {
    int kb = kc * 4 + lq;
    s16x8 af = *(const s16x8*)(&As[arow * DH + ((kb ^ (arow & 15)) * 8)]);
#pragma unroll
    for (int cf = 0; cf < 8; ++cf) {
      int bcol = cf * 16 + li;
      s16x8 bf = *(const s16x8*)(&Bs[bcol * DH + ((kb ^ (bcol & 15)) * 8)]);
      acc[cf] = __builtin_amdgcn_mfma_f32_16x16x32_bf16(af, bf, acc[cf], 0, 0, 0);
    }
  }

  int Rw = R0 + w * 16;
  // fused el/er: lane holds D[row=lq*4+r][col=cf*16+li]
  float alv[8], arv[8];
#pragma unroll
  for (int cf = 0; cf < 8; ++cf) {
    alv[cf] = al[cf * 16 + li];
    arv[cf] = ar[cf * 16 + li];
  }
#pragma unroll
  for (int r = 0; r < 4; ++r) {
    float sl = 0.f, sr = 0.f;
#pragma unroll
    for (int cf = 0; cf < 8; ++cf) {
      sl += acc[cf][r] * alv[cf];
      sr += acc[cf][r] * arv[cf];
    }
#pragma unroll
    for (int off = 1; off <= 8; off <<= 1) {
      sl += __shfl_xor(sl, off);
      sr += __shfl_xor(sr, off);
    }
    int grow = Rw + lq * 4 + r;
    if (li == 0 && grow < M) {
      el[grow] = sl;
      er[grow] = sr;
    }
  }

  // h store via LDS repack. Each wave reads/writes ONLY its own 16 As rows.
  ushort* hl = &As[w * 16 * DH];
#pragma unroll
  for (int cf = 0; cf < 8; ++cf)
#pragma unroll
    for (int r = 0; r < 4; ++r) hl[(lq * 4 + r) * DH + cf * 16 + li] = f2bf(acc[cf][r]);
#pragma unroll
  for (int p = 0; p < 4; ++p) {
    int row = lane >> 2;
    int blk = (lane & 3) + p * 4;
    s16x8 v = *(const s16x8*)(&hl[row * DH + blk * 8]);
    int grow = Rw + row;
    if (grow < M)
      __builtin_nontemporal_store(v, (s16x8*)(hb + (size_t)grow * DH + blk * 8));
  }
}

// ---------------- bf16-input GEMM (layers 1,2) ----------------
__global__ __launch_bounds__(512) void gemm_kernel(const ushort* __restrict__ xin,
                                                   const ushort* __restrict__ Wtb,
                                                   const float* __restrict__ al,
                                                   const float* __restrict__ ar,
                                                   ushort* __restrict__ hb,
                                                   float* __restrict__ el,
                                                   float* __restrict__ er, int M) {
  __shared__ ushort As[128 * DH];
  __shared__ ushort Bs[DH * DH];
  gemm_body<false>(As, Bs, xin, Wtb, al, ar, hb, el, er, M, blockIdx.x * 128, threadIdx.x);
}

// ---------------- fused layer-0 GEMM (fp32 input) + chist (independent work) ----------------
__global__ __launch_bounds__(512) void gemm0_chist_kernel(const float* __restrict__ feat,
                                                          const ushort* __restrict__ Wtb,
                                                          const float* __restrict__ al,
                                                          const float* __restrict__ ar,
                                                          ushort* __restrict__ hb,
                                                          float* __restrict__ el,
                                                          float* __restrict__ er, int M,
                                                          const int* __restrict__ dst,
                                                          int* __restrict__ chist, int E, int NB,
                                                          int GB) {
  __shared__ ushort As[128 * DH];
  __shared__ ushort Bs[DH * DH];
  int b = blockIdx.x, t = threadIdx.x;
  if (b < GB) {
    gemm_body<true>(As, Bs, feat, Wtb, al, ar, hb, el, er, M, b * 128, t);
    return;
  }
  // chist role: LDS histogram aliases As (4 KB needed)
  int* h = (int*)As;
  for (int i = t; i < NB; i += 512) h[i] = 0;
  __syncthreads();
  int base = (b - GB) * BCH;
  int n = min(BCH, E - base);
  for (int i0 = 0; i0 < n; i0 += 2048) {
    uint d[4]; bool ok[4];
#pragma unroll
    for (int k = 0; k < 4; ++k) {
      int i = i0 + k * 512 + t;
      ok[k] = i < n;
      d[k] = ok[k] ? (uint)dst[base + i] : 0u;
    }
#pragma unroll
    for (int k = 0; k < 4; ++k)
      if (ok[k]) atomicAdd(&h[d[k] >> 7], 1);
  }
  __syncthreads();
  for (int i = t; i < NB; i += 512)
    if (h[i]) atomicAdd(&chist[i * 16], h[i]);
}

// ---------------- CSR scan ----------------
__global__ __launch_bounds__(256) void cscan_kernel(const int* __restrict__ chist,
                                                    int* __restrict__ cbase, int* __restrict__ ccur,
                                                    int* __restrict__ rowptr, int N, int NB, int E) {
  __shared__ int lds[256];
  int t = threadIdx.x;
  int v[4], s = 0;
#pragma unroll
  for (int j = 0; j < 4; ++j) {
    int idx = t * 4 + j;
    v[j] = (idx < NB) ? chist[idx * 16] : 0;
    s += v[j];
  }
  lds[t] = s;
  __syncthreads();
  for (int off = 1; off < 256; off <<= 1) {
    int add = (t >= off) ? lds[t - off] : 0;
    __syncthreads();
    lds[t] += add;
    __syncthreads();
  }
  int run = t ? lds[t - 1] : 0;
#pragma unroll
  for (int j = 0; j < 4; ++j) {
    int idx = t * 4 + j;
    if (idx < NB) {
      cbase[idx] = run;
      ccur[idx * 16] = run;
    }
    run += v[j];
  }
  if (t == 255) cbase[NB] = lds[255];
  if (t == 0) rowptr[N] = E;
}

// ---------------- binscat: 8-deep predicated batches ----------------
__global__ __launch_bounds__(256) void binscat_kernel(const int* __restrict__ src,
                                                      const int* __restrict__ dst,
                                                      int* __restrict__ ccur,
                                                      uint* __restrict__ puv, int E, int NB) {
  __shared__ int h[NBMAX];
  __shared__ int gb[NBMAX];
  int t = threadIdx.x;
  int base = blockIdx.x * BCH;
  int n = min(BCH, E - base);
  for (int i = t; i < NB; i += 256) h[i] = 0;
  __syncthreads();
  for (int i0 = 0; i0 < n; i0 += 2048) {
    uint d[8]; bool ok[8];
#pragma unroll
    for (int k = 0; k < 8; ++k) {
      int i = i0 + k * 256 + t;
      ok[k] = i < n;
      d[k] = ok[k] ? (uint)dst[base + i] : 0u;
    }
#pragma unroll
    for (int k = 0; k < 8; ++k)
      if (ok[k]) atomicAdd(&h[d[k] >> 7], 1);
  }
  __syncthreads();
  // reserve a contiguous run per bin for this block; reset h as local cursor
  for (int i = t; i < NB; i += 256) {
    int c = h[i];
    gb[i] = c ? atomicAdd(&ccur[i * 16], c) : 0;
    h[i] = 0;
  }
  __syncthreads();
  for (int i0 = 0; i0 < n; i0 += 2048) {
    uint d[8], s[8]; bool ok[8];
#pragma unroll
    for (int k = 0; k < 8; ++k) {
      int i = i0 + k * 256 + t;
      ok[k] = i < n;
      d[k] = ok[k] ? (uint)dst[base + i] : 0u;
      s[k] = ok[k] ? (uint)src[base + i] : 0u;
    }
    int p[8];
#pragma unroll
    for (int k = 0; k < 8; ++k)
      if (ok[k]) {
        int bb = d[k] >> 7;
        p[k] = gb[bb] + atomicAdd(&h[bb], 1);
      }
#pragma unroll
    for (int k = 0; k < 8; ++k)
      if (ok[k]) puv[p[k]] = ((d[k] & 127u) << 25) | s[k];
  }
}

// ---------------- finesort: 8-deep predicated batches ----------------
__global__ __launch_bounds__(256) void finesort_kernel(const uint* __restrict__ puv,
                                                       const int* __restrict__ cbase,
                                                       int* __restrict__ rowptr,
                                                       int* __restrict__ ssrc, int N) {
  int b = blockIdx.x;
  int base = cbase[b];
  int cnt = cbase[b + 1] - base;
  __shared__ int ncnt[128], nincl[128], noff[128];
  int t = threadIdx.x;
  if (t < 128) ncnt[t] = 0;
  __syncthreads();
  for (int i0 = 0; i0 < cnt; i0 += 2048) {
    uint e[8]; bool ok[8];
#pragma unroll
    for (int k = 0; k < 8; ++k) {
      int i = i0 + k * 256 + t;
      ok[k] = i < cnt;
      e[k] = ok[k] ? puv[base + i] : 0u;
    }
#pragma unroll
    for (int k = 0; k < 8; ++k)
      if (ok[k]) atomicAdd(&ncnt[e[k] >> 25], 1);
  }
  __syncthreads();
  if (t < 128) nincl[t] = ncnt[t];
  __syncthreads();
  for (int off = 1; off < 128; off <<= 1) {
    int add = (t < 128 && t >= off) ? nincl[t - off] : 0;
    __syncthreads();
    if (t < 128) nincl[t] += add;
    __syncthreads();
  }
  if (t < 128) {
    noff[t] = nincl[t] - ncnt[t];
    int node = (b << 7) + t;
    if (node < N) rowptr[node] = base + noff[t];
    ncnt[t] = 0;  // reuse as cursor
  }
  __syncthreads();
  for (int i0 = 0; i0 < cnt; i0 += 2048) {
    uint e[8]; bool ok[8];
#pragma unroll
    for (int k = 0; k < 8; ++k) {
      int i = i0 + k * 256 + t;
      ok[k] = i < cnt;
      e[k] = ok[k] ? puv[base + i] : 0u;
    }
    int p[8];
#pragma unroll
    for (int k = 0; k < 8; ++k)
      if (ok[k]) {
        int ln = e[k] >> 25;
        p[k] = base + noff[ln] + atomicAdd(&ncnt[ln], 1);
      }
#pragma unroll
    for (int k = 0; k < 8; ++k)
      if (ok[k]) ssrc[p[k]] = (int)(e[k] & 0x1FFFFFFu);
  }
}

// ---------------- fused edge-softmax + aggregation (one wave per dst node) ----------------
// Quad-edge gathers: 16 lanes x 16B cover one 256B row; a wave processes 4
// edges per load instruction (q = lane>>4 picks the edge). Padded edge slots
// have wgt=0 and idx=0 (row-0 loads are cache-hot, contribute nothing).
// FINAL=0: write bf16 xb (non-temporal); FINAL=1: write fp32 d_out.
template <int FINAL>
__global__ __launch_bounds__(256) void agg_kernel(const ushort* __restrict__ hb,
                                                  const float* __restrict__ el,
                                                  const float* __restrict__ er,
                                                  const int* __restrict__ rowptr,
                                                  const int* __restrict__ ssrc,
                                                  const float* __restrict__ bias,
                                                  void* __restrict__ outv, int M) {
  int wid = (blockIdx.x * blockDim.x + threadIdx.x) >> 6;  // node id
  int lane = threadIdx.x & 63;
  if (wid >= M) return;
  int begin = rowptr[wid], end = rowptr[wid + 1];
  int deg = end - begin;

  if (deg > 64) {  // rare high-degree path: self-contained, float2-per-lane
    float er_d = er[wid];
    float mx = -1e30f;
    for (int e = begin + lane; e < end; e += 64) {
      float s = el[ssrc[e]] + er_d;
      s = s > 0.f ? s : 0.2f * s;
      mx = fmaxf(mx, s);
    }
#pragma unroll
    for (int off = 32; off; off >>= 1) mx = fmaxf(mx, __shfl_xor(mx, off));
    float acc0 = 0.f, acc1 = 0.f, ssum_l = 0.f;
    for (int base = begin; base < end; base += 64) {
      int n = min(64, end - base);
      int e = base + lane;
      int idx = 0;
      float wgt = 0.f;
      if (lane < n) {
        idx = ssrc[e];
        float sc = el[idx] + er_d;
        sc = sc > 0.f ? sc : 0.2f * sc;
        wgt = __expf(sc - mx);
      }
      ssum_l += wgt;
      for (int j = 0; j < n; ++j) {
        int s = __shfl(idx, j);
        float wg = __shfl(wgt, j);
        uint u = ((const uint*)(hb + (size_t)s * DH))[lane];
        acc0 += wg * bfl2f(u);
        acc1 += wg * bfh2f(u);
      }
    }
#pragma unroll
    for (int off = 32; off; off >>= 1) ssum_l += __shfl_xor(ssum_l, off);
    float inv = 1.f / ssum_l;
    float2 b2 = ((const float2*)bias)[lane];
    float o0 = acc0 * inv + b2.x;
    float o1 = acc1 * inv + b2.y;
    if constexpr (FINAL) {
      ((float2*)((float*)outv + (size_t)wid * DH))[lane] = make_float2(o0, o1);
    } else {
      uint p = (uint)f2bf(o0) | ((uint)f2bf(o1) << 16);
      ((uint*)((ushort*)outv + (size_t)wid * DH))[lane] = p;
    }
    return;
  }

  float acc[8] = {};
  float inv = 0.f;
  if (deg > 0) {
    // lane j owns edge begin+j: index, el-gather, leaky, exp all lane-parallel
    int e = begin + lane;
    int idx = (e < end) ? ssrc[e] : 0;
    float sc = -1e30f;
    if (e < end) {
      sc = el[idx] + er[wid];
      sc = sc > 0.f ? sc : 0.2f * sc;
    }
    float mx = sc;
#pragma unroll
    for (int off = 32; off; off >>= 1) mx = fmaxf(mx, __shfl_xor(mx, off));
    float wgt = (e < end) ? __expf(sc - mx) : 0.f;
    float ssum = wgt;
#pragma unroll
    for (int off = 32; off; off >>= 1) ssum += __shfl_xor(ssum, off);
    inv = 1.f / ssum;

    int q = lane >> 4, cl = lane & 15;
    const uint4* hb4 = (const uint4*)hb;  // row = 16 uint4
    for (int j = 0; j < deg; j += 16) {  // 16 edges per step (4 quads in flight)
      uint4 u[4];
      float wq[4];
#pragma unroll
      for (int k = 0; k < 4; ++k) {
        int ej = j + k * 4 + q;  // < 64 guaranteed (deg<=64, j<=48)
        int s = __shfl(idx, ej);
        wq[k] = __shfl(wgt, ej);
        u[k] = hb4[(size_t)s * 16 + cl];
      }
#pragma unroll
      for (int k = 0; k < 4; ++k) {
        acc[0] += wq[k] * bfl2f(u[k].x); acc[1] += wq[k] * bfh2f(u[k].x);
        acc[2] += wq[k] * bfl2f(u[k].y); acc[3] += wq[k] * bfh2f(u[k].y);
        acc[4] += wq[k] * bfl2f(u[k].z); acc[5] += wq[k] * bfh2f(u[k].z);
        acc[6] += wq[k] * bfl2f(u[k].w); acc[7] += wq[k] * bfh2f(u[k].w);
      }
    }
    // combine the 4 edge-quarters: lanes sharing (lane&15) sum up
#pragma unroll
    for (int i = 0; i < 8; ++i) {
      acc[i] += __shfl_xor(acc[i], 16);
      acc[i] += __shfl_xor(acc[i], 32);
    }
  }
  // deg==0: acc=0, inv=0 -> out = bias
  if (lane < 16) {
    float4 b0 = ((const float4*)bias)[lane * 2];
    float4 b1 = ((const float4*)bias)[lane * 2 + 1];
    float o[8];
    o[0] = acc[0] * inv + b0.x; o[1] = acc[1] * inv + b0.y;
    o[2] = acc[2] * inv + b0.z; o[3] = acc[3] * inv + b0.w;
    o[4] = acc[4] * inv + b1.x; o[5] = acc[5] * inv + b1.y;
    o[6] = acc[6] * inv + b1.z; o[7] = acc[7] * inv + b1.w;
    if constexpr (FINAL) {
      f32x4 p0 = {o[0], o[1], o[2], o[3]};
      f32x4 p1 = {o[4], o[5], o[6], o[7]};
      float* op = (float*)outv + (size_t)wid * DH + lane * 8;
      *(f32x4*)op = p0;
      *(f32x4*)(op + 4) = p1;
    } else {
      u32x4 p;
      p.x = (uint)f2bf(o[0]) | ((uint)f2bf(o[1]) << 16);
      p.y = (uint)f2bf(o[2]) | ((uint)f2bf(o[3]) << 16);
      p.z = (uint)f2bf(o[4]) | ((uint)f2bf(o[5]) << 16);
      p.w = (uint)f2bf(o[6]) | ((uint)f2bf(o[7]) << 16);
      __builtin_nontemporal_store(p, (u32x4*)((ushort*)outv + (size_t)wid * DH) + lane);
    }
  }
}

extern "C" void kernel_launch(void* const* d_in, const int* in_sizes, int n_in,
                              void* d_out, int out_size, void* d_ws, size_t ws_size,
                              hipStream_t stream) {
  const float* feat = (const float*)d_in[0];
  const int* src = (const int*)d_in[1];
  const int* dst = (const int*)d_in[2];
  const int N = in_sizes[0] / DH;  // 100000
  const int E = in_sizes[1];       // 1600000
  const int NB = (N + 127) >> 7;   // 782 coarse bins
  const float* W[3]  = {(const float*)d_in[3], (const float*)d_in[7],  (const float*)d_in[11]};
  const float* al[3] = {(const float*)d_in[4], (const float*)d_in[8],  (const float*)d_in[12]};
  const float* ar[3] = {(const float*)d_in[5], (const float*)d_in[9],  (const float*)d_in[13]};
  const float* bi[3] = {(const float*)d_in[6], (const float*)d_in[10], (const float*)d_in[14]};

  // workspace layout (~59 MB)
  char* ws = (char*)d_ws;
  size_t off = 0;
  auto alloc = [&](size_t bytes) {
    void* p = ws + off;
    off = (off + bytes + 255) & ~(size_t)255;
    return p;
  };
  ushort* hb   = (ushort*)alloc((size_t)N * DH * sizeof(ushort));  // 25.6 MB
  ushort* xb   = (ushort*)alloc((size_t)N * DH * sizeof(ushort));  // 25.6 MB
  float* el    = (float*)alloc((size_t)N * sizeof(float));
  float* er    = (float*)alloc((size_t)N * sizeof(float));
  int* rowptr  = (int*)alloc((size_t)(N + 1) * sizeof(int));
  int* ssrc    = (int*)alloc((size_t)E * sizeof(int));             // 6.4 MB
  ushort* Wtb  = (ushort*)alloc((size_t)3 * DH * DH * sizeof(ushort));
  int* chist   = (int*)alloc((size_t)NBMAX * 16 * sizeof(int));    // 64 KB padded
  int* cbase   = (int*)alloc((size_t)(NBMAX + 1) * sizeof(int));
  int* ccur    = (int*)alloc((size_t)NBMAX * 16 * sizeof(int));    // 64 KB padded
  // puv aliases xb: dead before agg0 writes xb, used only by binscat/finesort
  uint* puv    = (uint*)xb;

  int ebl = (E + BCH - 1) / BCH;   // 391
  int GB = (N + 127) / 128;        // 782 gemm tiles

  // ---- prep: Wt transpose (all layers) + chist zero ----
  prep_kernel<<<104, 512, 0, stream>>>(W[0], W[1], W[2], Wtb, chist);
  // ---- layer-0 GEMM fused with chist (independent work streams) ----
  gemm0_chist_kernel<<<GB + ebl, 512, 0, stream>>>(feat, Wtb, al[0], ar[0], hb, el, er, N,
                                                   dst, chist, E, NB, GB);
  // ---- rest of CSR build ----
  cscan_kernel<<<1, 256, 0, stream>>>(chist, cbase, ccur, rowptr, N, NB, E);
  binscat_kernel<<<ebl, 256, 0, stream>>>(src, dst, ccur, puv, E, NB);
  finesort_kernel<<<NB, 256, 0, stream>>>(puv, cbase, rowptr, ssrc, N);

  // ---- layer 0 agg, then layers 1,2 ----
  agg_kernel<0><<<(N + 3) / 4, 256, 0, stream>>>(hb, el, er, rowptr, ssrc, bi[0], xb, N);
  gemm_kernel<<<GB, 512, 0, stream>>>(xb, Wtb + DH * DH, al[1], ar[1], hb, el, er, N);
  agg_kernel<0><<<(N + 3) / 4, 256, 0, stream>>>(hb, el, er, rowptr, ssrc, bi[1], xb, N);
  gemm_kernel<<<GB, 512, 0, stream>>>(xb, Wtb + 2 * DH * DH, al[2], ar[2], hb, el, er, N);
  agg_kernel<1><<<(N + 3) / 4, 256, 0, stream>>>(hb, el, er, rowptr, ssrc, bi[2], d_out, N);
}